// Round 1
// baseline (366.744 us; speedup 1.0000x reference)
//
#include <hip/hip_runtime.h>
#include <math.h>

#define D 128
#define LSTRIDE 136   // LDS row stride in halves

typedef _Float16 half8 __attribute__((ext_vector_type(8)));
typedef _Float16 half4v __attribute__((ext_vector_type(4)));
typedef float f32x4 __attribute__((ext_vector_type(4)));

// ============ fat1: edge count + within-bucket rank, plus weight pre-pack ============

__global__ void k_fat1(const int* __restrict__ ei, int* __restrict__ counts,
                       int* __restrict__ pidx, int E, int countBlocks,
                       const float* __restrict__ convW, _Float16* __restrict__ Wf) {
    if ((int)blockIdx.x < countBlocks) {
        int e0 = (blockIdx.x * blockDim.x + threadIdx.x) * 4;
        if (e0 + 3 < E) {
            int4 d4 = *(const int4*)(ei + E + e0);
            int4 p;
            p.x = atomicAdd(&counts[d4.x], 1);
            p.y = atomicAdd(&counts[d4.y], 1);
            p.z = atomicAdd(&counts[d4.z], 1);
            p.w = atomicAdd(&counts[d4.w], 1);
            *(int4*)(pidx + e0) = p;
        } else {
            for (int e = e0; e < E; e++) pidx[e] = atomicAdd(&counts[ei[E + e]], 1);
        }
    } else {
        // prepw: slot = (s*8+c)*64 + lane; elem j: k = s*32+(lane>>4)*8+j, n = c*16+(lane&15)
        const int bid = blockIdx.x - countBlocks;           // 0..31
        const int l = bid >> 3;                             // layer
        const int slot = (bid & 7) * 256 + threadIdx.x;
        const float* W = convW + (size_t)l * D * D;
        const int p = slot >> 6, ln = slot & 63;
        const int s = p >> 3, c = p & 7;
        const int kbase = s * 32 + ((ln >> 4) << 3);
        const int n = (c << 4) + (ln & 15);
        half8 hv;
#pragma unroll
        for (int j = 0; j < 8; j++) hv[j] = (_Float16)W[(size_t)(kbase + j) * D + n];
        *(half8*)(Wf + (size_t)l * D * D + (size_t)slot * 8) = hv;
    }
}

// scan over PADDED counts (ceil4) -> rowptrP (16B-aligned row starts);
// emits dinv = rsqrt(count+1) and rend = start + count (pre-offset).
__global__ __launch_bounds__(256) void k_scan1(const int* __restrict__ counts,
                                               int* __restrict__ rowptrP,
                                               int* __restrict__ rend,
                                               int* __restrict__ bsums,
                                               float* __restrict__ dinv, int N) {
    __shared__ int sh[256];
    const int t = threadIdx.x;
    const int base = blockIdx.x * 1024 + t * 4;
    int c[4], pj[4];
#pragma unroll
    for (int j = 0; j < 4; j++) {
        c[j] = (base + j < N) ? counts[base + j] : 0;
        pj[j] = (c[j] + 3) & ~3;
    }
#pragma unroll
    for (int j = 0; j < 4; j++)
        if (base + j < N) dinv[base + j] = rsqrtf((float)(c[j] + 1));
    int tsum = pj[0] + pj[1] + pj[2] + pj[3];
    sh[t] = tsum;
    __syncthreads();
    for (int off = 1; off < 256; off <<= 1) {
        int v = (t >= off) ? sh[t - off] : 0;
        __syncthreads();
        sh[t] += v;
        __syncthreads();
    }
    int run = (t == 0) ? 0 : sh[t - 1];
    if (t == 255) bsums[blockIdx.x] = sh[255];
#pragma unroll
    for (int j = 0; j < 4; j++) {
        if (base + j <= N) {
            rowptrP[base + j] = run;
            if (base + j < N) rend[base + j] = run + c[j];
        }
        run += pj[j];
    }
}

// ============ fat2: scan3 (add block prefix; write padding SENTINELS) + cvt ============
// Sentinel slots [rend, rowptrP+pad4) get src = N (a zeroed row), so k_layer's
// gather loop is a uniform multiple of 4 — no remainder, no rend load.

__global__ __launch_bounds__(256) void k_fat2(int* __restrict__ rowptrP,
                                              int* __restrict__ rend,
                                              const int* __restrict__ bsums,
                                              int NB, int N, int scanBlocks,
                                              const float* __restrict__ x,
                                              const float* __restrict__ dinv,
                                              _Float16* __restrict__ g16,
                                              _Float16* __restrict__ g16b,
                                              int* __restrict__ srcs) {
    if ((int)blockIdx.x < scanBlocks) {
        __shared__ int pre[128];
        const int t = threadIdx.x;
        if (t < 128) pre[t] = (t < NB) ? bsums[t] : 0;
        __syncthreads();
        for (int off = 1; off < 128; off <<= 1) {
            int v = (t >= off && t < 128) ? pre[t - off] : 0;
            __syncthreads();
            if (t < 128) pre[t] += v;
            __syncthreads();
        }
        int i = blockIdx.x * blockDim.x + t;
        if (i <= N) {
            int b = i >> 10;
            int add = (b == 0) ? 0 : pre[b - 1];
            int rp = rowptrP[i] + add;
            rowptrP[i] = rp;
            if (i < N) {
                int re_ = rend[i] + add;
                rend[i] = re_;
                int pad = (-(re_ - rp)) & 3;          // 0..3 sentinel slots
                for (int k2 = 0; k2 < pad; k2++) srcs[re_ + k2] = N;
            }
        }
    } else {
        int i = (blockIdx.x - scanBlocks) * blockDim.x + threadIdx.x;
        const int n8 = N * (D / 8);
        if (i >= n8) {
            // zero the sentinel row (index N) in BOTH ping-pong buffers
            if (i < n8 + (D / 8)) {
                half8 zz;
#pragma unroll
                for (int j = 0; j < 8; j++) zz[j] = (_Float16)0.f;
                *(half8*)(g16 + (size_t)i * 8) = zz;
                *(half8*)(g16b + (size_t)i * 8) = zz;
            }
            return;
        }
        float s = dinv[i >> 4];
        const float4 v0 = *(const float4*)(x + (size_t)i * 8);
        const float4 v1 = *(const float4*)(x + (size_t)i * 8 + 4);
        half8 h;
        h[0] = (_Float16)(v0.x * s); h[1] = (_Float16)(v0.y * s);
        h[2] = (_Float16)(v0.z * s); h[3] = (_Float16)(v0.w * s);
        h[4] = (_Float16)(v1.x * s); h[5] = (_Float16)(v1.y * s);
        h[6] = (_Float16)(v1.z * s); h[7] = (_Float16)(v1.w * s);
        *(half8*)(g16 + (size_t)i * 8) = h;
    }
}

// pass B: srcs[rowptrP[dst] + pidx] = src — no atomics
__global__ void k_fill(const int* __restrict__ ei, const int* __restrict__ rowptrP,
                       const int* __restrict__ pidx, int* __restrict__ srcs, int E) {
    int e0 = (blockIdx.x * blockDim.x + threadIdx.x) * 4;
    if (e0 + 3 < E) {
        int4 s4 = *(const int4*)(ei + e0);
        int4 d4 = *(const int4*)(ei + E + e0);
        int4 p4 = *(const int4*)(pidx + e0);
        int r0 = rowptrP[d4.x], r1 = rowptrP[d4.y], r2 = rowptrP[d4.z], r3 = rowptrP[d4.w];
        srcs[r0 + p4.x] = s4.x;
        srcs[r1 + p4.y] = s4.y;
        srcs[r2 + p4.z] = s4.z;
        srcs[r3 + p4.w] = s4.w;
    } else {
        for (int e = e0; e < E; e++)
            srcs[rowptrP[ei[E + e]] + pidx[e]] = ei[e];
    }
}

// ============ fused layer: gout = scale ⊙ relu( (dinv ⊙ Â g) @ W + b ) ============
// 256 thr / 64 nodes per block. Phase 1 INTERLEAVES the group's 4 nodes:
// all index int4s issued, then all 16 row-gathers, then accumulate — 4× the
// outstanding misses of the old sequential-per-node structure. Sentinel-padded
// adjacency (multiple of 4, src=N -> zero row) removes the remainder loop and
// the rend load. Barrier-free (wave-local LDS reuse).

__global__ __launch_bounds__(256, 4) void k_layer(
        const _Float16* __restrict__ gin,
        const int* __restrict__ rowptrP,
        const int* __restrict__ srcs,
        const float* __restrict__ dinv,
        const _Float16* __restrict__ Wf,
        const float* __restrict__ bias,
        _Float16* __restrict__ gout, int N, int last) {
    __shared__ _Float16 S[64 * LSTRIDE];   // 17.4 KB

    const int tid  = threadIdx.x;
    const int w    = tid >> 6;        // wave 0..3
    const int lane = tid & 63;
    const int q    = lane >> 4;       // group 0..3
    const int l16  = lane & 15;       // lane-in-group; col base = l16*8
    const int nb0  = blockIdx.x * 64;
    const int cb   = l16 * 8;

    // ---- phase 1: interleaved gather; group q owns nodes q*4 + 0..3 ----
    int nd[4], bg[4], nc[4];
    float sc[4];
    float a[4][8];
#pragma unroll
    for (int it = 0; it < 4; it++) {
        const int node = nb0 + w * 16 + q * 4 + it;
        nd[it] = node;
        const bool vv = node < N;
        const int r0 = vv ? rowptrP[node] : 0;
        const int r1 = vv ? rowptrP[node + 1] : 0;
        bg[it] = r0;
        nc[it] = (r1 - r0) >> 2;      // padded -> exact chunk count
        sc[it] = vv ? dinv[node] : 0.f;
    }
    // self-loop rows (4 independent loads in flight)
#pragma unroll
    for (int it = 0; it < 4; it++) {
        if (nd[it] < N) {
            half8 sv = *(const half8*)(gin + (size_t)nd[it] * D + cb);
#pragma unroll
            for (int j = 0; j < 8; j++) a[it][j] = (float)sv[j];
        } else {
#pragma unroll
            for (int j = 0; j < 8; j++) a[it][j] = 0.f;
        }
    }

    int mx = nc[0] > nc[1] ? nc[0] : nc[1];
    mx = mx > nc[2] ? mx : nc[2];
    mx = mx > nc[3] ? mx : nc[3];

    for (int ch = 0; ch < mx; ch++) {
        int4 s4[4];
#pragma unroll
        for (int it = 0; it < 4; it++)
            if (ch < nc[it]) s4[it] = *(const int4*)(srcs + bg[it] + ch * 4);
#pragma unroll
        for (int it = 0; it < 4; it++) {
            if (ch < nc[it]) {
                half8 v0 = *(const half8*)(gin + (size_t)s4[it].x * D + cb);
                half8 v1 = *(const half8*)(gin + (size_t)s4[it].y * D + cb);
                half8 v2 = *(const half8*)(gin + (size_t)s4[it].z * D + cb);
                half8 v3 = *(const half8*)(gin + (size_t)s4[it].w * D + cb);
#pragma unroll
                for (int j = 0; j < 8; j++)
                    a[it][j] += ((float)v0[j] + (float)v1[j]) + ((float)v2[j] + (float)v3[j]);
            }
        }
    }

#pragma unroll
    for (int it = 0; it < 4; it++) {
        const int nl = w * 16 + q * 4 + it;
        half8 o;
#pragma unroll
        for (int j = 0; j < 8; j++) o[j] = (_Float16)(a[it][j] * sc[it]);
        *(half8*)(&S[nl * LSTRIDE + cb]) = o;
    }

    // wave-local LDS write->read ordering (no block barrier)
    asm volatile("s_waitcnt lgkmcnt(0)" ::: "memory");

    // ---- phase 2: S @ W via MFMA (A_op = W frag from global/L2, B_op = S frag) ----
    f32x4 acc[8];
#pragma unroll
    for (int cc = 0; cc < 8; cc++) acc[cc] = (f32x4){0.f, 0.f, 0.f, 0.f};

    const int nl2 = w * 16 + l16;          // this lane's node row (B-frag)
#pragma unroll
    for (int s = 0; s < 4; s++) {
        half8 bf = *(const half8*)(&S[nl2 * LSTRIDE + s * 32 + q * 8]);
#pragma unroll
        for (int cc = 0; cc < 8; cc++) {
            half8 wh = *(const half8*)(Wf + (size_t)((s * 8 + cc) * 64 + lane) * 8);
            acc[cc] = __builtin_amdgcn_mfma_f32_16x16x32_f16(wh, bf, acc[cc], 0, 0, 0);
        }
    }

    // epilogue: D[m = W-col = q*4+r][n = node = l16]
    const int node2 = nb0 + nl2;
    if (node2 < N) {
        const float scale = last ? 1.0f : dinv[node2];
        _Float16* rp = gout + (size_t)node2 * D + q * 4;
#pragma unroll
        for (int cc = 0; cc < 8; cc++) {
            const float4 bc = *(const float4*)(bias + cc * 16 + q * 4);
            half4v o;
            o[0] = (_Float16)(fmaxf(acc[cc][0] + bc.x, 0.f) * scale);
            o[1] = (_Float16)(fmaxf(acc[cc][1] + bc.y, 0.f) * scale);
            o[2] = (_Float16)(fmaxf(acc[cc][2] + bc.z, 0.f) * scale);
            o[3] = (_Float16)(fmaxf(acc[cc][3] + bc.w, 0.f) * scale);
            *(half4v*)(rp + cc * 16) = o;   // 8 B store
        }
    }
}

// ========== fused pool + MLP head: one block (256 thr) per graph ==========

__global__ __launch_bounds__(256) void k_poolhead(
        const _Float16* __restrict__ h, const int* __restrict__ batch,
        const float* __restrict__ W1, const float* __restrict__ b1,
        const float* __restrict__ W2, const float* __restrict__ b2,
        const float* __restrict__ W3, const float* __restrict__ b3,
        float* __restrict__ out, int N) {
    __shared__ int sb[2];
    __shared__ float part[16][D];
    __shared__ float pool[D];
    __shared__ float z[D];
    __shared__ float red[D];

    const int g = blockIdx.x;
    const int t = threadIdx.x;

    if (t < 2) {
        int target = g + t;
        int lo = 0, hi = N;
        while (lo < hi) {
            int mid = (lo + hi) >> 1;
            if (batch[mid] < target) lo = mid + 1; else hi = mid;
        }
        sb[t] = lo;
    }
    __syncthreads();
    const int rs = sb[0], re = sb[1];

    const int w = t >> 6;
    const int lane = t & 63;
    const int rw = w * 4 + (lane >> 4);   // 0..15: row-slot within the 16-row stride
    const int c8 = (lane & 15) * 8;

    float ax[8];
#pragma unroll
    for (int j = 0; j < 8; j++) ax[j] = 0.f;
    for (int r = rs + rw; r < re; r += 16) {
        half8 vv = *(const half8*)(h + (size_t)r * D + c8);
#pragma unroll
        for (int j = 0; j < 8; j++) ax[j] += (float)vv[j];
    }
#pragma unroll
    for (int j = 0; j < 8; j++) part[rw][c8 + j] = ax[j];
    __syncthreads();

    if (t < D) {
        float s = 0.f;
#pragma unroll
        for (int gg = 0; gg < 16; gg++) s += part[gg][t];
        pool[t] = s;
    }
    __syncthreads();

    if (t < D) {
        float s = b1[t];
        for (int k = 0; k < D; k++) s = fmaf(pool[k], W1[(size_t)k * D + t], s);
        z[t] = fmaxf(s, 0.f);
    }
    __syncthreads();

    if (t < D) {
        float s = b2[t];
        for (int k = 0; k < D; k++) s = fmaf(z[k], W2[(size_t)k * D + t], s);
        red[t] = fmaxf(s, 0.f) * W3[t];
    }
    __syncthreads();
    for (int off = 64; off >= 1; off >>= 1) {
        if (t < off) red[t] += red[t + off];
        __syncthreads();
    }
    if (t == 0) out[g] = 1.f / (1.f + expf(-(red[0] + b3[0])));
}

// ================= orchestration =================

extern "C" void kernel_launch(void* const* d_in, const int* in_sizes, int n_in,
                              void* d_out, int out_size, void* d_ws, size_t ws_size,
                              hipStream_t stream) {
    const float* x     = (const float*)d_in[0];
    const int*   ei    = (const int*)d_in[1];
    const int*   batch = (const int*)d_in[2];
    const float* convW = (const float*)d_in[3];
    const float* convB = (const float*)d_in[4];
    const float* W1 = (const float*)d_in[5];
    const float* b1 = (const float*)d_in[6];
    const float* W2 = (const float*)d_in[7];
    const float* b2 = (const float*)d_in[8];
    const float* W3 = (const float*)d_in[9];
    const float* b3 = (const float*)d_in[10];
    float* out = (float*)d_out;

    const int N = in_sizes[0] / D;          // 100000
    const int E = in_sizes[1] / 2;          // 640000
    const int G = out_size;                 // 512
    const int NB = (N + 1023) / 1024;

    // ---- workspace layout ----
    char* w = (char*)d_ws;
    size_t off = 0;
    auto alloc = [&](size_t bytes) -> char* {
        char* p = w + off;
        off += (bytes + 255) & ~(size_t)255;
        return p;
    };
    float*     dinv   = (float*)alloc((size_t)N * 4);
    _Float16*  gA     = (_Float16*)alloc((size_t)(N + 1) * D * 2);  // +1 sentinel row
    _Float16*  gB     = (_Float16*)alloc((size_t)(N + 1) * D * 2);
    _Float16*  Wf     = (_Float16*)alloc((size_t)4 * D * D * 2);
    int*       counts = (int*)alloc((size_t)N * 4);
    int*       rowptrP= (int*)alloc((size_t)(N + 1) * 4);
    int*       rend   = (int*)alloc((size_t)N * 4);
    int*       pidx   = (int*)alloc((size_t)E * 4);
    int*       srcs   = (int*)alloc((size_t)(E + 3 * N) * 4);
    int*       bsums  = (int*)alloc((size_t)NB * 4);

    // ---- CSR build + weight pre-pack + input convert ----
    hipMemsetAsync(counts, 0, (size_t)N * 4, stream);
    const int countBlocks = (E / 4 + 255) / 256;
    k_fat1<<<countBlocks + 32, 256, 0, stream>>>(ei, counts, pidx, E, countBlocks,
                                                 convW, Wf);
    k_scan1<<<NB, 256, 0, stream>>>(counts, rowptrP, rend, bsums, dinv, N);
    const int scanBlocks = (N + 1 + 255) / 256;
    const int cvtBlocks  = ((N + 1) * (D / 8) + 255) / 256;
    k_fat2<<<scanBlocks + cvtBlocks, 256, 0, stream>>>(rowptrP, rend, bsums, NB, N,
                                                       scanBlocks, x, dinv, gA, gB,
                                                       srcs);
    k_fill<<<(E / 4 + 255) / 256, 256, 0, stream>>>(ei, rowptrP, pidx, srcs, E);

    // ---- 4 fused GCN layers (ping-pong) ----
    const int layer_grid = (N + 63) / 64;
    const _Float16* gi = gA;
    _Float16* go = gB;
    for (int l = 0; l < 4; l++) {
        k_layer<<<layer_grid, 256, 0, stream>>>(gi, rowptrP, srcs, dinv,
                                                Wf + (size_t)l * D * D,
                                                convB + (size_t)l * D,
                                                go, N, l == 3);
        const _Float16* tmp = go;
        go = (_Float16*)gi;
        gi = tmp;
    }

    // ---- fused pool + head ----
    k_poolhead<<<G, 256, 0, stream>>>(gi, batch, W1, b1, W2, b2, W3, b3, out, N);
}

// Round 2
// 357.284 us; speedup vs baseline: 1.0265x; 1.0265x over previous
//
#include <hip/hip_runtime.h>
#include <math.h>

#define D 128
#define LSTRIDE 136   // LDS row stride in halves

typedef _Float16 half8 __attribute__((ext_vector_type(8)));
typedef _Float16 half4v __attribute__((ext_vector_type(4)));
typedef _Float16 half2v __attribute__((ext_vector_type(2)));
typedef float f32x4 __attribute__((ext_vector_type(4)));

// ============ fat1: edge count + within-bucket rank, plus weight pre-pack ============

__global__ void k_fat1(const int* __restrict__ ei, int* __restrict__ counts,
                       int* __restrict__ pidx, int E, int countBlocks,
                       const float* __restrict__ convW, _Float16* __restrict__ Wf) {
    if ((int)blockIdx.x < countBlocks) {
        int e0 = (blockIdx.x * blockDim.x + threadIdx.x) * 4;
        if (e0 + 3 < E) {
            int4 d4 = *(const int4*)(ei + E + e0);
            int4 p;
            p.x = atomicAdd(&counts[d4.x], 1);
            p.y = atomicAdd(&counts[d4.y], 1);
            p.z = atomicAdd(&counts[d4.z], 1);
            p.w = atomicAdd(&counts[d4.w], 1);
            *(int4*)(pidx + e0) = p;
        } else {
            for (int e = e0; e < E; e++) pidx[e] = atomicAdd(&counts[ei[E + e]], 1);
        }
    } else {
        // prepw: slot = (s*8+c)*64 + lane; elem j: k = s*32+(lane>>4)*8+j, n = c*16+(lane&15)
        const int bid = blockIdx.x - countBlocks;           // 0..31
        const int l = bid >> 3;                             // layer
        const int slot = (bid & 7) * 256 + threadIdx.x;
        const float* W = convW + (size_t)l * D * D;
        const int p = slot >> 6, ln = slot & 63;
        const int s = p >> 3, c = p & 7;
        const int kbase = s * 32 + ((ln >> 4) << 3);
        const int n = (c << 4) + (ln & 15);
        half8 hv;
#pragma unroll
        for (int j = 0; j < 8; j++) hv[j] = (_Float16)W[(size_t)(kbase + j) * D + n];
        *(half8*)(Wf + (size_t)l * D * D + (size_t)slot * 8) = hv;
    }
}

// scan over PADDED counts (ceil4) -> rowptrP (16B-aligned row starts);
// emits dinv = rsqrt(count+1), rend = start + count, AND a 64-bin degree
// histogram (for the degree-sorted node permutation).
__global__ __launch_bounds__(256) void k_scan1(const int* __restrict__ counts,
                                               int* __restrict__ rowptrP,
                                               int* __restrict__ rend,
                                               int* __restrict__ bsums,
                                               float* __restrict__ dinv,
                                               int* __restrict__ degHist, int N) {
    __shared__ int sh[256];
    __shared__ int lh[64];
    const int t = threadIdx.x;
    const int base = blockIdx.x * 1024 + t * 4;
    int c[4], pj[4];
#pragma unroll
    for (int j = 0; j < 4; j++) {
        c[j] = (base + j < N) ? counts[base + j] : 0;
        pj[j] = (c[j] + 3) & ~3;
    }
#pragma unroll
    for (int j = 0; j < 4; j++)
        if (base + j < N) dinv[base + j] = rsqrtf((float)(c[j] + 1));

    // ---- degree histogram (block-local then one global add per bin) ----
    if (t < 64) lh[t] = 0;
    __syncthreads();
#pragma unroll
    for (int j = 0; j < 4; j++)
        if (base + j < N) atomicAdd(&lh[c[j] < 63 ? c[j] : 63], 1);
    __syncthreads();
    if (t < 64 && lh[t]) atomicAdd(&degHist[t], lh[t]);

    int tsum = pj[0] + pj[1] + pj[2] + pj[3];
    sh[t] = tsum;
    __syncthreads();
    for (int off = 1; off < 256; off <<= 1) {
        int v = (t >= off) ? sh[t - off] : 0;
        __syncthreads();
        sh[t] += v;
        __syncthreads();
    }
    int run = (t == 0) ? 0 : sh[t - 1];
    if (t == 255) bsums[blockIdx.x] = sh[255];
#pragma unroll
    for (int j = 0; j < 4; j++) {
        if (base + j <= N) {
            rowptrP[base + j] = run;
            if (base + j < N) rend[base + j] = run + c[j];
        }
        run += pj[j];
    }
}

// ============ fat2: scan3 (add block prefix to rowptrP & rend) + cvt ============

__global__ __launch_bounds__(256) void k_fat2(int* __restrict__ rowptrP,
                                              int* __restrict__ rend,
                                              const int* __restrict__ bsums,
                                              int NB, int N, int scanBlocks,
                                              const float* __restrict__ x,
                                              const float* __restrict__ dinv,
                                              _Float16* __restrict__ g16) {
    if ((int)blockIdx.x < scanBlocks) {
        __shared__ int pre[128];
        const int t = threadIdx.x;
        if (t < 128) pre[t] = (t < NB) ? bsums[t] : 0;
        __syncthreads();
        for (int off = 1; off < 128; off <<= 1) {
            int v = (t >= off && t < 128) ? pre[t - off] : 0;
            __syncthreads();
            if (t < 128) pre[t] += v;
            __syncthreads();
        }
        int i = blockIdx.x * blockDim.x + t;
        if (i <= N) {
            int b = i >> 10;
            int add = (b == 0) ? 0 : pre[b - 1];
            rowptrP[i] += add;
            if (i < N) rend[i] += add;
        }
    } else {
        int i = (blockIdx.x - scanBlocks) * blockDim.x + threadIdx.x;
        const int n8 = N * (D / 8);
        if (i >= n8) return;
        float s = dinv[i >> 4];
        const float4 v0 = *(const float4*)(x + (size_t)i * 8);
        const float4 v1 = *(const float4*)(x + (size_t)i * 8 + 4);
        half8 h;
        h[0] = (_Float16)(v0.x * s); h[1] = (_Float16)(v0.y * s);
        h[2] = (_Float16)(v0.z * s); h[3] = (_Float16)(v0.w * s);
        h[4] = (_Float16)(v1.x * s); h[5] = (_Float16)(v1.y * s);
        h[6] = (_Float16)(v1.z * s); h[7] = (_Float16)(v1.w * s);
        *(half8*)(g16 + (size_t)i * 8) = h;
    }
}

// pass B: srcs[rowptrP[dst] + pidx] = src — no atomics.
// Extra blocks build perm[] = nodes sorted by DESCENDING degree (LPT schedule):
// 64-bin counting sort; block-local ranks + per-bin global cursors.
__global__ void k_fill(const int* __restrict__ ei, const int* __restrict__ rowptrP,
                       const int* __restrict__ pidx, int* __restrict__ srcs, int E,
                       int fillBlocks, int N, const int* __restrict__ counts,
                       const int* __restrict__ degHist, int* __restrict__ degCur,
                       int* __restrict__ perm) {
    if ((int)blockIdx.x < fillBlocks) {
        int e0 = (blockIdx.x * blockDim.x + threadIdx.x) * 4;
        if (e0 + 3 < E) {
            int4 s4 = *(const int4*)(ei + e0);
            int4 d4 = *(const int4*)(ei + E + e0);
            int4 p4 = *(const int4*)(pidx + e0);
            int r0 = rowptrP[d4.x], r1 = rowptrP[d4.y], r2 = rowptrP[d4.z], r3 = rowptrP[d4.w];
            srcs[r0 + p4.x] = s4.x;
            srcs[r1 + p4.y] = s4.y;
            srcs[r2 + p4.z] = s4.z;
            srcs[r3 + p4.w] = s4.w;
        } else {
            for (int e = e0; e < E; e++)
                srcs[rowptrP[ei[E + e]] + pidx[e]] = ei[e];
        }
    } else {
        __shared__ int lbase[64];   // global base of each bin (descending order)
        __shared__ int lh[64];      // block-local bin counts
        __shared__ int gb[64];      // this block's base within each bin
        const int t = threadIdx.x;
        const int i = ((int)blockIdx.x - fillBlocks) * blockDim.x + t;
        if (t < 64) lh[t] = 0;
        __syncthreads();
        int deg = 0, lrank = 0;
        const bool v = i < N;
        if (v) {
            int c = counts[i];
            deg = c < 63 ? c : 63;
            lrank = atomicAdd(&lh[deg], 1);
        }
        __syncthreads();
        if (t < 64) gb[t] = lh[t] ? atomicAdd(&degCur[t], lh[t]) : 0;
        if (t == 0) {
            int run = 0;
            for (int d = 63; d >= 0; d--) { lbase[d] = run; run += degHist[d]; }
        }
        __syncthreads();
        if (v) perm[lbase[deg] + gb[deg] + lrank] = i;
    }
}

// ============ fused layer: gout = scale ⊙ relu( (dinv ⊙ Â g) @ W + b ) ============
// Round-0 gather structure (sequential per node, VGPR-lean) + degree-sorted
// node permutation: wave slot i processes node perm[i], so all 16 nodes in a
// wave have near-equal degree (lockstep groups don't wait on a straggler) and
// descending order gives LPT block scheduling. 256 thr / 64 nodes per block
// for finer residency granularity. Barrier-free (wave-local LDS reuse).

__global__ __launch_bounds__(256) void k_layer(
        const _Float16* __restrict__ gin,
        const int* __restrict__ rowptrP, const int* __restrict__ rend,
        const int* __restrict__ srcs,
        const float* __restrict__ dinv,
        const int* __restrict__ perm,
        const _Float16* __restrict__ Wf,
        const float* __restrict__ bias,
        _Float16* __restrict__ gout, int N, int last) {
    __shared__ _Float16 S[64 * LSTRIDE];   // 17.4 KB

    const int tid  = threadIdx.x;
    const int w    = tid >> 6;        // wave 0..3
    const int lane = tid & 63;
    const int q    = lane >> 4;       // group 0..3
    const int l16  = lane & 15;       // lane-in-group; col base = l16*8
    const int nb0  = blockIdx.x * 64;
    const int cb   = l16 * 8;

    // ---- phase 1: gather; wave w covers slots w*16..+15, group q owns q*4+it ----
    int pn[4];
#pragma unroll
    for (int it = 0; it < 4; it++) {
        const int slot = nb0 + w * 16 + q * 4 + it;
        pn[it] = (slot < N) ? perm[slot] : -1;
    }

    for (int it = 0; it < 4; ++it) {
        const int nl = w * 16 + q * 4 + it;
        const int node = pn[it];
        float a[8];
#pragma unroll
        for (int j = 0; j < 8; j++) a[j] = 0.f;

        if (node >= 0) {
            half8 sv = *(const half8*)(gin + (size_t)node * D + cb);  // self-loop
#pragma unroll
            for (int j = 0; j < 8; j++) a[j] = (float)sv[j];
            int e = rowptrP[node];                 // 4-aligned
            const int end = rend[node];
            for (; e + 3 < end; e += 4) {
                int4 s4 = *(const int4*)(srcs + e);   // one 16 B index load
                half8 v0 = *(const half8*)(gin + (size_t)s4.x * D + cb);
                half8 v1 = *(const half8*)(gin + (size_t)s4.y * D + cb);
                half8 v2 = *(const half8*)(gin + (size_t)s4.z * D + cb);
                half8 v3 = *(const half8*)(gin + (size_t)s4.w * D + cb);
#pragma unroll
                for (int j = 0; j < 8; j++)
                    a[j] += ((float)v0[j] + (float)v1[j]) + ((float)v2[j] + (float)v3[j]);
            }
            for (; e < end; e++) {
                int s0 = srcs[e];
                half8 v0 = *(const half8*)(gin + (size_t)s0 * D + cb);
#pragma unroll
                for (int j = 0; j < 8; j++) a[j] += (float)v0[j];
            }
        }
        const float sc = (node >= 0) ? dinv[node] : 0.f;
        half8 o;
#pragma unroll
        for (int j = 0; j < 8; j++) o[j] = (_Float16)(a[j] * sc);
        *(half8*)(&S[nl * LSTRIDE + cb]) = o;
    }

    // wave-local LDS write->read ordering (no block barrier)
    asm volatile("s_waitcnt lgkmcnt(0)" ::: "memory");

    // ---- phase 2: S @ W via MFMA (A_op = W frag from global/L2, B_op = S frag) ----
    f32x4 acc[8];
#pragma unroll
    for (int cc = 0; cc < 8; cc++) acc[cc] = (f32x4){0.f, 0.f, 0.f, 0.f};

    const int nl2 = w * 16 + l16;          // this lane's slot row (B-frag)
#pragma unroll
    for (int s = 0; s < 4; s++) {
        half8 bf = *(const half8*)(&S[nl2 * LSTRIDE + s * 32 + q * 8]);
#pragma unroll
        for (int cc = 0; cc < 8; cc++) {
            half8 wh = *(const half8*)(Wf + (size_t)((s * 8 + cc) * 64 + lane) * 8);
            acc[cc] = __builtin_amdgcn_mfma_f32_16x16x32_f16(wh, bf, acc[cc], 0, 0, 0);
        }
    }

    // epilogue: D[m = W-col = q*4+r][n = slot = l16] -> node perm[slot]
    const int slot2 = nb0 + nl2;
    const int node2 = (slot2 < N) ? perm[slot2] : -1;
    if (node2 >= 0) {
        const float scale = last ? 1.0f : dinv[node2];
        _Float16* rp = gout + (size_t)node2 * D + q * 4;
#pragma unroll
        for (int cc = 0; cc < 8; cc++) {
            const float4 bc = *(const float4*)(bias + cc * 16 + q * 4);
            half4v o;
            o[0] = (_Float16)(fmaxf(acc[cc][0] + bc.x, 0.f) * scale);
            o[1] = (_Float16)(fmaxf(acc[cc][1] + bc.y, 0.f) * scale);
            o[2] = (_Float16)(fmaxf(acc[cc][2] + bc.z, 0.f) * scale);
            o[3] = (_Float16)(fmaxf(acc[cc][3] + bc.w, 0.f) * scale);
            *(half4v*)(rp + cc * 16) = o;   // 8 B store
        }
    }
}

// ========== fused pool + MLP head: one block (256 thr) per graph ==========

__global__ __launch_bounds__(256) void k_poolhead(
        const _Float16* __restrict__ h, const int* __restrict__ batch,
        const float* __restrict__ W1, const float* __restrict__ b1,
        const float* __restrict__ W2, const float* __restrict__ b2,
        const float* __restrict__ W3, const float* __restrict__ b3,
        float* __restrict__ out, int N) {
    __shared__ int sb[2];
    __shared__ float part[16][D];
    __shared__ float pool[D];
    __shared__ float z[D];
    __shared__ float red[D];

    const int g = blockIdx.x;
    const int t = threadIdx.x;

    if (t < 2) {
        int target = g + t;
        int lo = 0, hi = N;
        while (lo < hi) {
            int mid = (lo + hi) >> 1;
            if (batch[mid] < target) lo = mid + 1; else hi = mid;
        }
        sb[t] = lo;
    }
    __syncthreads();
    const int rs = sb[0], re = sb[1];

    const int w = t >> 6;
    const int lane = t & 63;
    const int rw = w * 4 + (lane >> 4);   // 0..15: row-slot within the 16-row stride
    const int c8 = (lane & 15) * 8;

    float ax[8];
#pragma unroll
    for (int j = 0; j < 8; j++) ax[j] = 0.f;
    for (int r = rs + rw; r < re; r += 16) {
        half8 vv = *(const half8*)(h + (size_t)r * D + c8);
#pragma unroll
        for (int j = 0; j < 8; j++) ax[j] += (float)vv[j];
    }
#pragma unroll
    for (int j = 0; j < 8; j++) part[rw][c8 + j] = ax[j];
    __syncthreads();

    if (t < D) {
        float s = 0.f;
#pragma unroll
        for (int gg = 0; gg < 16; gg++) s += part[gg][t];
        pool[t] = s;
    }
    __syncthreads();

    if (t < D) {
        float s = b1[t];
        for (int k = 0; k < D; k++) s = fmaf(pool[k], W1[(size_t)k * D + t], s);
        z[t] = fmaxf(s, 0.f);
    }
    __syncthreads();

    if (t < D) {
        float s = b2[t];
        for (int k = 0; k < D; k++) s = fmaf(z[k], W2[(size_t)k * D + t], s);
        red[t] = fmaxf(s, 0.f) * W3[t];
    }
    __syncthreads();
    for (int off = 64; off >= 1; off >>= 1) {
        if (t < off) red[t] += red[t + off];
        __syncthreads();
    }
    if (t == 0) out[g] = 1.f / (1.f + expf(-(red[0] + b3[0])));
}

// ================= orchestration =================

extern "C" void kernel_launch(void* const* d_in, const int* in_sizes, int n_in,
                              void* d_out, int out_size, void* d_ws, size_t ws_size,
                              hipStream_t stream) {
    const float* x     = (const float*)d_in[0];
    const int*   ei    = (const int*)d_in[1];
    const int*   batch = (const int*)d_in[2];
    const float* convW = (const float*)d_in[3];
    const float* convB = (const float*)d_in[4];
    const float* W1 = (const float*)d_in[5];
    const float* b1 = (const float*)d_in[6];
    const float* W2 = (const float*)d_in[7];
    const float* b2 = (const float*)d_in[8];
    const float* W3 = (const float*)d_in[9];
    const float* b3 = (const float*)d_in[10];
    float* out = (float*)d_out;

    const int N = in_sizes[0] / D;          // 100000
    const int E = in_sizes[1] / 2;          // 640000
    const int G = out_size;                 // 512
    const int NB = (N + 1023) / 1024;

    // ---- workspace layout ----
    char* w = (char*)d_ws;
    size_t off = 0;
    auto alloc = [&](size_t bytes) -> char* {
        char* p = w + off;
        off += (bytes + 255) & ~(size_t)255;
        return p;
    };
    float*     dinv   = (float*)alloc((size_t)N * 4);
    _Float16*  gA     = (_Float16*)alloc((size_t)N * D * 2);
    _Float16*  gB     = (_Float16*)alloc((size_t)N * D * 2);
    _Float16*  Wf     = (_Float16*)alloc((size_t)4 * D * D * 2);
    int*       counts = (int*)alloc((size_t)(N + 128) * 4);  // + degHist[64] + degCur[64]
    int*       degHist= counts + N;
    int*       degCur = counts + N + 64;
    int*       rowptrP= (int*)alloc((size_t)(N + 1) * 4);
    int*       rend   = (int*)alloc((size_t)N * 4);
    int*       pidx   = (int*)alloc((size_t)E * 4);
    int*       srcs   = (int*)alloc((size_t)(E + 3 * N) * 4);
    int*       bsums  = (int*)alloc((size_t)NB * 4);
    int*       perm   = (int*)alloc((size_t)N * 4);

    // ---- CSR build + weight pre-pack + input convert + degree sort ----
    hipMemsetAsync(counts, 0, (size_t)(N + 128) * 4, stream);
    const int countBlocks = (E / 4 + 255) / 256;
    k_fat1<<<countBlocks + 32, 256, 0, stream>>>(ei, counts, pidx, E, countBlocks,
                                                 convW, Wf);
    k_scan1<<<NB, 256, 0, stream>>>(counts, rowptrP, rend, bsums, dinv, degHist, N);
    const int scanBlocks = (N + 1 + 255) / 256;
    const int cvtBlocks  = (N * (D / 8) + 255) / 256;
    k_fat2<<<scanBlocks + cvtBlocks, 256, 0, stream>>>(rowptrP, rend, bsums, NB, N,
                                                       scanBlocks, x, dinv, gA);
    const int fillBlocks = (E / 4 + 255) / 256;
    const int rankBlocks = (N + 255) / 256;
    k_fill<<<fillBlocks + rankBlocks, 256, 0, stream>>>(ei, rowptrP, pidx, srcs, E,
                                                        fillBlocks, N, counts,
                                                        degHist, degCur, perm);

    // ---- 4 fused GCN layers (ping-pong) ----
    const int layer_grid = (N + 63) / 64;
    const _Float16* gi = gA;
    _Float16* go = gB;
    for (int l = 0; l < 4; l++) {
        k_layer<<<layer_grid, 256, 0, stream>>>(gi, rowptrP, rend, srcs, dinv, perm,
                                                Wf + (size_t)l * D * D,
                                                convB + (size_t)l * D,
                                                go, N, l == 3);
        const _Float16* tmp = go;
        go = (_Float16*)gi;
        gi = tmp;
    }

    // ---- fused pool + head ----
    k_poolhead<<<G, 256, 0, stream>>>(gi, batch, W1, b1, W2, b2, W3, b3, out, N);
}

// Round 3
// 348.839 us; speedup vs baseline: 1.0513x; 1.0242x over previous
//
#include <hip/hip_runtime.h>
#include <math.h>

#define D 128
#define LSTRIDE 136   // LDS row stride in halves

typedef _Float16 half8 __attribute__((ext_vector_type(8)));
typedef _Float16 half4v __attribute__((ext_vector_type(4)));
typedef float f32x4 __attribute__((ext_vector_type(4)));

// ============ fat1: edge count + within-bucket rank, plus weight pre-pack ============

__global__ void k_fat1(const int* __restrict__ ei, int* __restrict__ counts,
                       int* __restrict__ pidx, int E, int countBlocks,
                       const float* __restrict__ convW, _Float16* __restrict__ Wf) {
    if ((int)blockIdx.x < countBlocks) {
        int e0 = (blockIdx.x * blockDim.x + threadIdx.x) * 4;
        if (e0 + 3 < E) {
            int4 d4 = *(const int4*)(ei + E + e0);
            int4 p;
            p.x = atomicAdd(&counts[d4.x], 1);
            p.y = atomicAdd(&counts[d4.y], 1);
            p.z = atomicAdd(&counts[d4.z], 1);
            p.w = atomicAdd(&counts[d4.w], 1);
            *(int4*)(pidx + e0) = p;
        } else {
            for (int e = e0; e < E; e++) pidx[e] = atomicAdd(&counts[ei[E + e]], 1);
        }
    } else {
        // prepw: slot = (s*8+c)*64 + lane; elem j: k = s*32+(lane>>4)*8+j, n = c*16+(lane&15)
        const int bid = blockIdx.x - countBlocks;           // 0..31
        const int l = bid >> 3;                             // layer
        const int slot = (bid & 7) * 256 + threadIdx.x;
        const float* W = convW + (size_t)l * D * D;
        const int p = slot >> 6, ln = slot & 63;
        const int s = p >> 3, c = p & 7;
        const int kbase = s * 32 + ((ln >> 4) << 3);
        const int n = (c << 4) + (ln & 15);
        half8 hv;
#pragma unroll
        for (int j = 0; j < 8; j++) hv[j] = (_Float16)W[(size_t)(kbase + j) * D + n];
        *(half8*)(Wf + (size_t)l * D * D + (size_t)slot * 8) = hv;
    }
}

// scan over PADDED counts (ceil4) -> rowptrP (16B-aligned row starts);
// emits dinv = rsqrt(count+1) and a 64-bin degree histogram.
__global__ __launch_bounds__(256) void k_scan1(const int* __restrict__ counts,
                                               int* __restrict__ rowptrP,
                                               int* __restrict__ bsums,
                                               float* __restrict__ dinv,
                                               int* __restrict__ degHist, int N) {
    __shared__ int sh[256];
    __shared__ int lh[64];
    const int t = threadIdx.x;
    const int base = blockIdx.x * 1024 + t * 4;
    int c[4], pj[4];
#pragma unroll
    for (int j = 0; j < 4; j++) {
        c[j] = (base + j < N) ? counts[base + j] : 0;
        pj[j] = (c[j] + 3) & ~3;
    }
#pragma unroll
    for (int j = 0; j < 4; j++)
        if (base + j < N) dinv[base + j] = rsqrtf((float)(c[j] + 1));

    if (t < 64) lh[t] = 0;
    __syncthreads();
#pragma unroll
    for (int j = 0; j < 4; j++)
        if (base + j < N) atomicAdd(&lh[c[j] < 63 ? c[j] : 63], 1);
    __syncthreads();
    if (t < 64 && lh[t]) atomicAdd(&degHist[t], lh[t]);

    int tsum = pj[0] + pj[1] + pj[2] + pj[3];
    sh[t] = tsum;
    __syncthreads();
    for (int off = 1; off < 256; off <<= 1) {
        int v = (t >= off) ? sh[t - off] : 0;
        __syncthreads();
        sh[t] += v;
        __syncthreads();
    }
    int run = (t == 0) ? 0 : sh[t - 1];
    if (t == 255) bsums[blockIdx.x] = sh[255];
#pragma unroll
    for (int j = 0; j < 4; j++) {
        if (base + j <= N) rowptrP[base + j] = run;
        run += pj[j];
    }
}

// ============ fat2: scan3 (block prefix + sentinel pads into srcs) + counting-sort ============

__global__ __launch_bounds__(256) void k_fat2(int* __restrict__ rowptrP,
                                              const int* __restrict__ counts,
                                              const int* __restrict__ bsums,
                                              int NB, int N, int scanBlocks, int NS,
                                              int* __restrict__ srcs,
                                              const int* __restrict__ degHist,
                                              int* __restrict__ degCur,
                                              int* __restrict__ perm,
                                              int* __restrict__ rankOf) {
    if ((int)blockIdx.x < scanBlocks) {
        __shared__ int pre[128];
        const int t = threadIdx.x;
        if (t < 128) pre[t] = (t < NB) ? bsums[t] : 0;
        __syncthreads();
        for (int off = 1; off < 128; off <<= 1) {
            int v = (t >= off && t < 128) ? pre[t - off] : 0;
            __syncthreads();
            if (t < 128) pre[t] += v;
            __syncthreads();
        }
        int i = blockIdx.x * blockDim.x + t;
        if (i <= N) {
            int b = i >> 10;
            int add = (b == 0) ? 0 : pre[b - 1];
            int rp = rowptrP[i] + add;
            rowptrP[i] = rp;
            if (i < N) {
                int c = counts[i];
                int re_ = rp + c;
                int pad = (-c) & 3;                    // 0..3 sentinel slots
                for (int k2 = 0; k2 < pad; k2++) srcs[re_ + k2] = NS;
            }
        }
    } else {
        // counting-sort rank assignment: perm (desc by degree) + rankOf
        __shared__ int lbase[64], lh[64], gb[64];
        const int t = threadIdx.x;
        const int i = ((int)blockIdx.x - scanBlocks) * blockDim.x + t;
        if (t < 64) lh[t] = 0;
        __syncthreads();
        int deg = 0, lrank = 0;
        const bool v = i < N;
        if (v) {
            int c = counts[i];
            deg = c < 63 ? c : 63;
            lrank = atomicAdd(&lh[deg], 1);
        }
        __syncthreads();
        if (t < 64) gb[t] = lh[t] ? atomicAdd(&degCur[t], lh[t]) : 0;
        if (t == 0) {
            int run = 0;
            for (int d = 63; d >= 0; d--) { lbase[d] = run; run += degHist[d]; }
        }
        __syncthreads();
        if (v) {
            int r = lbase[deg] + gb[deg] + lrank;
            perm[r] = i;
            rankOf[i] = r;
        }
    }
}

// ============ fill: edges (rank-valued) + rank-space slot tables + rank-space cvt ============

__global__ void k_fill(const int* __restrict__ ei, const int* __restrict__ rowptrP,
                       const int* __restrict__ pidx, int* __restrict__ srcs, int E,
                       int fillBlocks, int slotBlocks, int N, int NS,
                       const int* __restrict__ rankOf,
                       const int* __restrict__ perm,
                       const float* __restrict__ dinv,
                       int* __restrict__ rbegR, int* __restrict__ rpenR,
                       float* __restrict__ dinvR, int* __restrict__ sentIdx,
                       const float* __restrict__ x,
                       _Float16* __restrict__ gA, _Float16* __restrict__ gB) {
    const int b = blockIdx.x;
    if (b < fillBlocks) {
        int e0 = (b * blockDim.x + threadIdx.x) * 4;
        if (e0 + 3 < E) {
            int4 s4 = *(const int4*)(ei + e0);
            int4 d4 = *(const int4*)(ei + E + e0);
            int4 p4 = *(const int4*)(pidx + e0);
            srcs[rowptrP[d4.x] + p4.x] = rankOf[s4.x];
            srcs[rowptrP[d4.y] + p4.y] = rankOf[s4.y];
            srcs[rowptrP[d4.z] + p4.z] = rankOf[s4.z];
            srcs[rowptrP[d4.w] + p4.w] = rankOf[s4.w];
        } else {
            for (int e = e0; e < E; e++)
                srcs[rowptrP[ei[E + e]] + pidx[e]] = rankOf[ei[e]];
        }
    } else if (b < fillBlocks + slotBlocks) {
        const int r = (b - fillBlocks) * blockDim.x + threadIdx.x;
        if (r == 0) { int4 sv; sv.x = sv.y = sv.z = sv.w = NS; *(int4*)sentIdx = sv; }
        if (r < NS) {
            if (r < N) {
                int p = perm[r];
                rbegR[r] = rowptrP[p];
                rpenR[r] = rowptrP[p + 1];    // padded end (next padded start)
                dinvR[r] = dinv[p];
            } else {
                rbegR[r] = 0; rpenR[r] = 0; dinvR[r] = 0.f;
            }
        }
    } else {
        // cvt x -> gA in RANK space (seq read, scattered 256B row write);
        // zero dummy rows [N, NS] (incl. sentinel row NS) in BOTH buffers.
        const int i = (b - fillBlocks - slotBlocks) * blockDim.x + threadIdx.x;
        const int TC = (NS + 1) * 16;
        if (i >= TC) return;
        const int row = i >> 4, j = i & 15;
        if (row < N) {
            const float s = dinv[row];
            const int rr = rankOf[row];
            const float4 v0 = *(const float4*)(x + (size_t)row * D + j * 8);
            const float4 v1 = *(const float4*)(x + (size_t)row * D + j * 8 + 4);
            half8 h;
            h[0] = (_Float16)(v0.x * s); h[1] = (_Float16)(v0.y * s);
            h[2] = (_Float16)(v0.z * s); h[3] = (_Float16)(v0.w * s);
            h[4] = (_Float16)(v1.x * s); h[5] = (_Float16)(v1.y * s);
            h[6] = (_Float16)(v1.z * s); h[7] = (_Float16)(v1.w * s);
            *(half8*)(gA + (size_t)rr * D + j * 8) = h;
        } else {
            half8 z;
#pragma unroll
            for (int j2 = 0; j2 < 8; j2++) z[j2] = (_Float16)0.f;
            *(half8*)(gA + (size_t)row * D + j * 8) = z;
            *(half8*)(gB + (size_t)row * D + j * 8) = z;
        }
    }
}

// ============ fused layer: gout = scale ⊙ relu( (dinv ⊙ Â g) @ W + b ) ============
// Rank-space: slot r = sorted rank; wave owns 16 equal-degree ranks (consecutive
// after counting sort) -> interleaved gather has no within-wave divergence.
// Branch-free: over-read chunks select a sentinel int4 ({NS,..} -> zero row NS);
// index int4s prefetched one chunk ahead. rowptr/dinv/self-row/stores coalesced.
// Last layer scatter-writes back to original node order via perm.

__global__ __launch_bounds__(256) void k_layer(
        const _Float16* __restrict__ gin,
        const int* __restrict__ rbegR, const int* __restrict__ rpenR,
        const int* __restrict__ srcs,
        const int* __restrict__ sentIdx,
        const float* __restrict__ dinvR,
        const int* __restrict__ perm,
        const _Float16* __restrict__ Wf,
        const float* __restrict__ bias,
        _Float16* __restrict__ gout, int N, int last) {
    __shared__ _Float16 S[64 * LSTRIDE];   // 17.4 KB

    const int tid  = threadIdx.x;
    const int w    = tid >> 6;        // wave 0..3
    const int lane = tid & 63;
    const int q    = lane >> 4;       // group 0..3
    const int l16  = lane & 15;       // lane-in-group; col base = l16*8
    const int sb   = blockIdx.x * 64; // slot base
    const int cb   = l16 * 8;
    const int slot0 = sb + w * 16 + q * 4;

    // ---- phase 1: branch-free interleaved gather over the group's 4 slots ----
    int bg[4], nc[4];
    int mx = 0;
#pragma unroll
    for (int it = 0; it < 4; it++) {
        bg[it] = rbegR[slot0 + it];
        nc[it] = (rpenR[slot0 + it] - bg[it]) >> 2;   // padded chunk count
        mx = nc[it] > mx ? nc[it] : mx;
    }

    float a[4][8];
#pragma unroll
    for (int it = 0; it < 4; it++) {                  // self-loop rows (coalesced)
        half8 sv = *(const half8*)(gin + (size_t)(slot0 + it) * D + cb);
#pragma unroll
        for (int j = 0; j < 8; j++) a[it][j] = (float)sv[j];
    }

    int4 cur[4];
#pragma unroll
    for (int it = 0; it < 4; it++) {
        const int* ip = (0 < nc[it]) ? (srcs + bg[it]) : sentIdx;
        cur[it] = *(const int4*)ip;
    }
    for (int ch = 0; ch < mx; ch++) {
        int4 nxt[4];
#pragma unroll
        for (int it = 0; it < 4; it++) {              // prefetch next chunk's indices
            const int* ip = (ch + 1 < nc[it]) ? (srcs + bg[it] + (ch + 1) * 4) : sentIdx;
            nxt[it] = *(const int4*)ip;
        }
#pragma unroll
        for (int it = 0; it < 4; it++) {              // 16 row loads in flight
            half8 v0 = *(const half8*)(gin + (size_t)cur[it].x * D + cb);
            half8 v1 = *(const half8*)(gin + (size_t)cur[it].y * D + cb);
            half8 v2 = *(const half8*)(gin + (size_t)cur[it].z * D + cb);
            half8 v3 = *(const half8*)(gin + (size_t)cur[it].w * D + cb);
#pragma unroll
            for (int j = 0; j < 8; j++)
                a[it][j] += ((float)v0[j] + (float)v1[j]) + ((float)v2[j] + (float)v3[j]);
        }
#pragma unroll
        for (int it = 0; it < 4; it++) cur[it] = nxt[it];
    }

#pragma unroll
    for (int it = 0; it < 4; it++) {
        const float sc = dinvR[slot0 + it];
        const int nl = w * 16 + q * 4 + it;
        half8 o;
#pragma unroll
        for (int j = 0; j < 8; j++) o[j] = (_Float16)(a[it][j] * sc);
        *(half8*)(&S[nl * LSTRIDE + cb]) = o;
    }

    // wave-local LDS write->read ordering (no block barrier)
    asm volatile("s_waitcnt lgkmcnt(0)" ::: "memory");

    // ---- phase 2: S @ W via MFMA (A_op = W frag from global/L2, B_op = S frag) ----
    f32x4 acc[8];
#pragma unroll
    for (int cc = 0; cc < 8; cc++) acc[cc] = (f32x4){0.f, 0.f, 0.f, 0.f};

    const int nl2 = w * 16 + l16;          // this lane's slot row (B-frag)
#pragma unroll
    for (int s = 0; s < 4; s++) {
        half8 bf = *(const half8*)(&S[nl2 * LSTRIDE + s * 32 + q * 8]);
#pragma unroll
        for (int cc = 0; cc < 8; cc++) {
            half8 wh = *(const half8*)(Wf + (size_t)((s * 8 + cc) * 64 + lane) * 8);
            acc[cc] = __builtin_amdgcn_mfma_f32_16x16x32_f16(wh, bf, acc[cc], 0, 0, 0);
        }
    }

    // epilogue: D[m = W-col = q*4+r][n = slot = l16]
    const int slot2 = sb + nl2;
    if (!last) {
        const float scale = dinvR[slot2];             // 0 for dummy slots -> stays 0
        _Float16* rp = gout + (size_t)slot2 * D + q * 4;
#pragma unroll
        for (int cc = 0; cc < 8; cc++) {
            const float4 bc = *(const float4*)(bias + cc * 16 + q * 4);
            half4v o;
            o[0] = (_Float16)(fmaxf(acc[cc][0] + bc.x, 0.f) * scale);
            o[1] = (_Float16)(fmaxf(acc[cc][1] + bc.y, 0.f) * scale);
            o[2] = (_Float16)(fmaxf(acc[cc][2] + bc.z, 0.f) * scale);
            o[3] = (_Float16)(fmaxf(acc[cc][3] + bc.w, 0.f) * scale);
            *(half4v*)(rp + cc * 16) = o;   // 8 B store, coalesced rows
        }
    } else if (slot2 < N) {
        const int node2 = perm[slot2];                // back to original order
        _Float16* rp = gout + (size_t)node2 * D + q * 4;
#pragma unroll
        for (int cc = 0; cc < 8; cc++) {
            const float4 bc = *(const float4*)(bias + cc * 16 + q * 4);
            half4v o;
            o[0] = (_Float16)fmaxf(acc[cc][0] + bc.x, 0.f);
            o[1] = (_Float16)fmaxf(acc[cc][1] + bc.y, 0.f);
            o[2] = (_Float16)fmaxf(acc[cc][2] + bc.z, 0.f);
            o[3] = (_Float16)fmaxf(acc[cc][3] + bc.w, 0.f);
            *(half4v*)(rp + cc * 16) = o;
        }
    }
}

// ========== fused pool + MLP head: one block (256 thr) per graph ==========

__global__ __launch_bounds__(256) void k_poolhead(
        const _Float16* __restrict__ h, const int* __restrict__ batch,
        const float* __restrict__ W1, const float* __restrict__ b1,
        const float* __restrict__ W2, const float* __restrict__ b2,
        const float* __restrict__ W3, const float* __restrict__ b3,
        float* __restrict__ out, int N) {
    __shared__ int sb[2];
    __shared__ float part[16][D];
    __shared__ float pool[D];
    __shared__ float z[D];
    __shared__ float red[D];

    const int g = blockIdx.x;
    const int t = threadIdx.x;

    if (t < 2) {
        int target = g + t;
        int lo = 0, hi = N;
        while (lo < hi) {
            int mid = (lo + hi) >> 1;
            if (batch[mid] < target) lo = mid + 1; else hi = mid;
        }
        sb[t] = lo;
    }
    __syncthreads();
    const int rs = sb[0], re = sb[1];

    const int w = t >> 6;
    const int lane = t & 63;
    const int rw = w * 4 + (lane >> 4);   // 0..15: row-slot within the 16-row stride
    const int c8 = (lane & 15) * 8;

    float ax[8];
#pragma unroll
    for (int j = 0; j < 8; j++) ax[j] = 0.f;
    for (int r = rs + rw; r < re; r += 16) {
        half8 vv = *(const half8*)(h + (size_t)r * D + c8);
#pragma unroll
        for (int j = 0; j < 8; j++) ax[j] += (float)vv[j];
    }
#pragma unroll
    for (int j = 0; j < 8; j++) part[rw][c8 + j] = ax[j];
    __syncthreads();

    if (t < D) {
        float s = 0.f;
#pragma unroll
        for (int gg = 0; gg < 16; gg++) s += part[gg][t];
        pool[t] = s;
    }
    __syncthreads();

    if (t < D) {
        float s = b1[t];
        for (int k = 0; k < D; k++) s = fmaf(pool[k], W1[(size_t)k * D + t], s);
        z[t] = fmaxf(s, 0.f);
    }
    __syncthreads();

    if (t < D) {
        float s = b2[t];
        for (int k = 0; k < D; k++) s = fmaf(z[k], W2[(size_t)k * D + t], s);
        red[t] = fmaxf(s, 0.f) * W3[t];
    }
    __syncthreads();
    for (int off = 64; off >= 1; off >>= 1) {
        if (t < off) red[t] += red[t + off];
        __syncthreads();
    }
    if (t == 0) out[g] = 1.f / (1.f + expf(-(red[0] + b3[0])));
}

// ================= orchestration =================

extern "C" void kernel_launch(void* const* d_in, const int* in_sizes, int n_in,
                              void* d_out, int out_size, void* d_ws, size_t ws_size,
                              hipStream_t stream) {
    const float* x     = (const float*)d_in[0];
    const int*   ei    = (const int*)d_in[1];
    const int*   batch = (const int*)d_in[2];
    const float* convW = (const float*)d_in[3];
    const float* convB = (const float*)d_in[4];
    const float* W1 = (const float*)d_in[5];
    const float* b1 = (const float*)d_in[6];
    const float* W2 = (const float*)d_in[7];
    const float* b2 = (const float*)d_in[8];
    const float* W3 = (const float*)d_in[9];
    const float* b3 = (const float*)d_in[10];
    float* out = (float*)d_out;

    const int N = in_sizes[0] / D;          // 100000
    const int E = in_sizes[1] / 2;          // 640000
    const int G = out_size;                 // 512
    const int NB = (N + 1023) / 1024;
    const int NS = ((N + 63) / 64) * 64;    // slot count (64-aligned); sentinel row = NS

    // ---- workspace layout ----
    char* w = (char*)d_ws;
    size_t off = 0;
    auto alloc = [&](size_t bytes) -> char* {
        char* p = w + off;
        off += (bytes + 255) & ~(size_t)255;
        return p;
    };
    float*     dinv   = (float*)alloc((size_t)N * 4);
    _Float16*  gA     = (_Float16*)alloc((size_t)(NS + 1) * D * 2);
    _Float16*  gB     = (_Float16*)alloc((size_t)(NS + 1) * D * 2);
    _Float16*  Wf     = (_Float16*)alloc((size_t)4 * D * D * 2);
    int*       counts = (int*)alloc((size_t)(N + 128) * 4);  // + degHist[64] + degCur[64]
    int*       degHist= counts + N;
    int*       degCur = counts + N + 64;
    int*       rowptrP= (int*)alloc((size_t)(N + 1) * 4);
    int*       pidx   = (int*)alloc((size_t)E * 4);
    int*       srcs   = (int*)alloc((size_t)(E + 3 * N) * 4);
    int*       bsums  = (int*)alloc((size_t)NB * 4);
    int*       perm   = (int*)alloc((size_t)N * 4);
    int*       rankOf = (int*)alloc((size_t)N * 4);
    int*       rbegR  = (int*)alloc((size_t)NS * 4);
    int*       rpenR  = (int*)alloc((size_t)NS * 4);
    float*     dinvR  = (float*)alloc((size_t)NS * 4);
    int*       sentIdx= (int*)alloc(16);

    // ---- CSR build + sort + rank-space tables + cvt ----
    hipMemsetAsync(counts, 0, (size_t)(N + 128) * 4, stream);
    const int countBlocks = (E / 4 + 255) / 256;
    k_fat1<<<countBlocks + 32, 256, 0, stream>>>(ei, counts, pidx, E, countBlocks,
                                                 convW, Wf);
    k_scan1<<<NB, 256, 0, stream>>>(counts, rowptrP, bsums, dinv, degHist, N);
    const int scanBlocks = (N + 1 + 255) / 256;
    const int rankBlocks = (N + 255) / 256;
    k_fat2<<<scanBlocks + rankBlocks, 256, 0, stream>>>(rowptrP, counts, bsums, NB, N,
                                                        scanBlocks, NS, srcs,
                                                        degHist, degCur, perm, rankOf);
    const int fillBlocks = (E / 4 + 255) / 256;
    const int slotBlocks = (NS + 255) / 256;
    const int cvtBlocks  = ((NS + 1) * 16 + 255) / 256;
    k_fill<<<fillBlocks + slotBlocks + cvtBlocks, 256, 0, stream>>>(
        ei, rowptrP, pidx, srcs, E, fillBlocks, slotBlocks, N, NS,
        rankOf, perm, dinv, rbegR, rpenR, dinvR, sentIdx, x, gA, gB);

    // ---- 4 fused GCN layers (ping-pong, rank space; last scatters to orig) ----
    const int layer_grid = NS / 64;
    const _Float16* gi = gA;
    _Float16* go = gB;
    for (int l = 0; l < 4; l++) {
        k_layer<<<layer_grid, 256, 0, stream>>>(gi, rbegR, rpenR, srcs, sentIdx,
                                                dinvR, perm,
                                                Wf + (size_t)l * D * D,
                                                convB + (size_t)l * D,
                                                go, N, l == 3);
        const _Float16* tmp = go;
        go = (_Float16*)gi;
        gi = tmp;
    }

    // ---- fused pool + head ----
    k_poolhead<<<G, 256, 0, stream>>>(gi, batch, W1, b1, W2, b2, W3, b3, out, N);
}